// Round 4
// baseline (369.024 us; speedup 1.0000x reference)
//
#include <hip/hip_runtime.h>

// B=1024, S=200, D=64, C=256
// out[0] cluster_emb  [B,C,D] f32, out[1] cluster_mask [B,C,S] f32 (0/1)
#define NB 1024
#define NS 200
#define ND 64
#define NC 256

typedef float v4f __attribute__((ext_vector_type(4)));

// ---------------------------------------------------------------------------
// K1: mask writer. One block = (batch, 64-cluster tile). LDS = 800 B only.
// R4: plain stores (NT stores measured ~2 TB/s effective; L2 write-back path
// hits 6.2 TB/s per the harness fill kernel).
// ---------------------------------------------------------------------------
__global__ __launch_bounds__(256) void s3rec_mask_kernel(
    const int* __restrict__ labels,  // [B,S]
    const int* __restrict__ amask,   // [B,S]
    float* __restrict__ out_mask)    // [B,C,S]
{
    __shared__ __align__(16) int s_lab[NS];

    const int bid = blockIdx.x;
    const int b   = bid >> 2;          // batch
    const int ct  = (bid & 3) << 6;    // cluster tile base (0,64,128,192)
    const int t   = threadIdx.x;

    for (int i = t; i < NS; i += 256) {
        const int l = labels[b * NS + i];
        const int m = amask [b * NS + i];
        s_lab[i] = (m != 0) ? l : -1;
    }
    __syncthreads();

    // 64 clusters x 200 seq = 12800 floats = 3200 vec4 per block.
    const int4* lab4 = reinterpret_cast<const int4*>(s_lab);
    v4f* om4 = reinterpret_cast<v4f*>(out_mask + (size_t)b * (NC * NS)) + ct * 50;
    for (int i4 = t; i4 < 64 * 50; i4 += 256) {
        const int cl = i4 / 50;
        const int s4 = i4 - cl * 50;
        const int c  = ct + cl;
        const int4 L = lab4[s4];           // ds_read_b128
        v4f v;
        v.x = (L.x == c) ? 1.0f : 0.0f;
        v.y = (L.y == c) ? 1.0f : 0.0f;
        v.z = (L.z == c) ? 1.0f : 0.0f;
        v.w = (L.w == c) ? 1.0f : 0.0f;
        om4[i4] = v;                       // plain store -> L2 write-back
    }
}

// ---------------------------------------------------------------------------
// K2: per-cluster mean embeddings. One block per batch; 64 KB LDS accumulator.
// ---------------------------------------------------------------------------
__global__ __launch_bounds__(256) void s3rec_emb_kernel(
    const float* __restrict__ x,       // [B,S,D]
    const int*   __restrict__ labels,  // [B,S]
    const int*   __restrict__ amask,   // [B,S]
    float* __restrict__ out_emb)       // [B,C,D]
{
    __shared__ __align__(16) float s_emb[NC * ND];   // 65536 B
    __shared__ int   s_lab[NS];
    __shared__ float s_inv[NC];

    const int b = blockIdx.x;
    const int t = threadIdx.x;

    for (int i = t; i < NS; i += 256) {
        const int l = labels[b * NS + i];
        const int m = amask [b * NS + i];
        s_lab[i] = (m != 0) ? l : -1;
    }
    v4f* se4 = reinterpret_cast<v4f*>(s_emb);
    for (int i = t; i < (NC * ND) / 4; i += 256) {
        v4f z = {0.0f, 0.0f, 0.0f, 0.0f};
        se4[i] = z;
    }
    __syncthreads();

    // Wave w takes s = w, w+4, ...; lane = d. Loads: 256B/wave coalesced.
    // LDS atomicAdd: 64 consecutive floats -> 2 lanes/bank (free).
    const int lane = t & 63;
    const int w    = t >> 6;
    const float* xb = x + (size_t)b * NS * ND;
    for (int s = w; s < NS; s += 4) {
        const int c = s_lab[s];
        if (c >= 0) {
            atomicAdd(&s_emb[c * ND + lane], xb[s * ND + lane]);
        }
    }

    int cnt = 0;
    #pragma unroll 8
    for (int s = 0; s < NS; ++s) cnt += (s_lab[s] == t) ? 1 : 0;
    s_inv[t] = (cnt > 0) ? (1.0f / (float)cnt) : 0.0f;
    __syncthreads();

    v4f* oe4 = reinterpret_cast<v4f*>(out_emb + (size_t)b * (NC * ND));
    for (int i4 = t; i4 < (NC * ND) / 4; i4 += 256) {
        const float inv = s_inv[i4 >> 4];
        v4f v = se4[i4] * inv;
        oe4[i4] = v;                       // plain store
    }
}

extern "C" void kernel_launch(void* const* d_in, const int* in_sizes, int n_in,
                              void* d_out, int out_size, void* d_ws, size_t ws_size,
                              hipStream_t stream) {
    const float* x      = (const float*)d_in[0];  // [B,S,D] f32
    const int*   labels = (const int*)  d_in[1];  // [B,S]   i32
    const int*   amask  = (const int*)  d_in[2];  // [B,S]   i32

    float* out_emb  = (float*)d_out;                   // [B,C,D]
    float* out_mask = out_emb + (size_t)NB * NC * ND;  // [B,C,S]

    s3rec_mask_kernel<<<dim3(NB * 4), dim3(256), 0, stream>>>(labels, amask, out_mask);
    s3rec_emb_kernel <<<dim3(NB),     dim3(256), 0, stream>>>(x, labels, amask, out_emb);
}

// Round 5
// 362.038 us; speedup vs baseline: 1.0193x; 1.0193x over previous
//
#include <hip/hip_runtime.h>

// B=1024, S=200, D=64, C=256
// out[0] cluster_emb  [B,C,D] f32 (16.8M), out[1] cluster_mask [B,C,S] f32 (52.4M)
#define NB 1024
#define NS 200
#define ND 64
#define NC 256

typedef float v4f __attribute__((ext_vector_type(4)));

// ---------------------------------------------------------------------------
// K1a: zero the mask region. Fill-style: grid-stride, zero per-store ALU/LDS
// dependency. 52,428,800 floats = 13,107,200 v4f. Should run at ~6 TB/s like
// the harness fill (which hits 6.1 TB/s at 9.6% occupancy).
// ---------------------------------------------------------------------------
__global__ __launch_bounds__(256) void s3rec_zero_mask(float* __restrict__ out_mask) {
    v4f* p = reinterpret_cast<v4f*>(out_mask);
    const v4f z = {0.0f, 0.0f, 0.0f, 0.0f};
    const int n4 = (NB * NC * NS) / 4;            // 13,107,200
    const int stride = gridDim.x * blockDim.x;    // 4096*256 = 1,048,576
    for (int i = blockIdx.x * blockDim.x + threadIdx.x; i < n4; i += stride)
        p[i] = z;
}

// ---------------------------------------------------------------------------
// K1b: scatter the ones. ~0.39 ones per cluster row; total ~100K scalar
// stores. One block per batch, threads 0..199 handle one seq position each.
// Runs after K1a on the same stream -> ordering guaranteed.
// ---------------------------------------------------------------------------
__global__ __launch_bounds__(256) void s3rec_scatter_ones(
    const int* __restrict__ labels,  // [B,S]
    const int* __restrict__ amask,   // [B,S]
    float* __restrict__ out_mask)    // [B,C,S]
{
    const int b = blockIdx.x;
    const int t = threadIdx.x;
    if (t < NS) {
        const int l = labels[b * NS + t];
        const int m = amask [b * NS + t];
        if (m != 0)
            out_mask[(size_t)b * (NC * NS) + (size_t)l * NS + t] = 1.0f;
    }
}

// ---------------------------------------------------------------------------
// K2: per-cluster mean embeddings. One block per batch; 64 KB LDS accumulator.
// Writes ALL C*D floats (zero rows included) so the zero-pass only needs to
// cover the mask region.
// ---------------------------------------------------------------------------
__global__ __launch_bounds__(256) void s3rec_emb_kernel(
    const float* __restrict__ x,       // [B,S,D]
    const int*   __restrict__ labels,  // [B,S]
    const int*   __restrict__ amask,   // [B,S]
    float* __restrict__ out_emb)       // [B,C,D]
{
    __shared__ __align__(16) float s_emb[NC * ND];   // 65536 B
    __shared__ __align__(16) int   s_lab[NS];
    __shared__ float s_inv[NC];

    const int b = blockIdx.x;
    const int t = threadIdx.x;

    for (int i = t; i < NS; i += 256) {
        const int l = labels[b * NS + i];
        const int m = amask [b * NS + i];
        s_lab[i] = (m != 0) ? l : -1;
    }
    v4f* se4 = reinterpret_cast<v4f*>(s_emb);
    for (int i = t; i < (NC * ND) / 4; i += 256) {
        v4f z = {0.0f, 0.0f, 0.0f, 0.0f};
        se4[i] = z;
    }
    __syncthreads();

    // Wave w takes s = w, w+4, ...; lane = d. Loads: 256B/wave coalesced.
    // LDS atomicAdd: 64 consecutive floats -> 2 lanes/bank (free, m136).
    const int lane = t & 63;
    const int w    = t >> 6;
    const float* xb = x + (size_t)b * NS * ND;
    for (int s = w; s < NS; s += 4) {
        const int c = s_lab[s];
        if (c >= 0) {
            atomicAdd(&s_emb[c * ND + lane], xb[s * ND + lane]);
        }
    }

    // thread t counts cluster t; int4 reads (broadcast across lanes, 50 iters)
    const int4* lab4 = reinterpret_cast<const int4*>(s_lab);
    int cnt = 0;
    #pragma unroll 10
    for (int s4 = 0; s4 < NS / 4; ++s4) {
        const int4 L = lab4[s4];
        cnt += (L.x == t) + (L.y == t) + (L.z == t) + (L.w == t);
    }
    s_inv[t] = (cnt > 0) ? (1.0f / (float)cnt) : 0.0f;
    __syncthreads();

    v4f* oe4 = reinterpret_cast<v4f*>(out_emb + (size_t)b * (NC * ND));
    for (int i4 = t; i4 < (NC * ND) / 4; i4 += 256) {
        const float inv = s_inv[i4 >> 4];
        v4f v = se4[i4] * inv;
        oe4[i4] = v;
    }
}

extern "C" void kernel_launch(void* const* d_in, const int* in_sizes, int n_in,
                              void* d_out, int out_size, void* d_ws, size_t ws_size,
                              hipStream_t stream) {
    const float* x      = (const float*)d_in[0];  // [B,S,D] f32
    const int*   labels = (const int*)  d_in[1];  // [B,S]   i32
    const int*   amask  = (const int*)  d_in[2];  // [B,S]   i32

    float* out_emb  = (float*)d_out;                   // [B,C,D]
    float* out_mask = out_emb + (size_t)NB * NC * ND;  // [B,C,S]

    s3rec_zero_mask   <<<dim3(4096), dim3(256), 0, stream>>>(out_mask);
    s3rec_scatter_ones<<<dim3(NB),   dim3(256), 0, stream>>>(labels, amask, out_mask);
    s3rec_emb_kernel  <<<dim3(NB),   dim3(256), 0, stream>>>(x, labels, amask, out_emb);
}